// Round 9
// baseline (731.907 us; speedup 1.0000x reference)
//
#include <hip/hip_runtime.h>
#include <cmath>

#define B_ROWS 16384
#define IN_DIM 784
#define N_HID  2000
#define K_WIN  200

// ---------------------------------------------------------------------------
// Phase 0: boost[i] = expf(0.1f - duty[i]);  w2t[i*12+c] = w2[c*2000+i]
// ---------------------------------------------------------------------------
__global__ __launch_bounds__(256) void prep_kernel(const float* __restrict__ duty,
                                                   const float* __restrict__ w2,
                                                   float* __restrict__ boost,
                                                   float* __restrict__ w2t) {
    int t = blockIdx.x * 256 + threadIdx.x;
    if (t < N_HID) boost[t] = expf(0.1f - duty[t]);
    if (t < N_HID * 10) {
        int i = t / 10, c = t - i * 10;
        w2t[i * 12 + c] = w2[c * N_HID + i];
    }
}

// ---------------------------------------------------------------------------
// Phase 1: h = x @ W1^T + b1, fp32.  Round-4 version VERBATIM (best: ~585 us,
// 85% of the m07 measured sustained full-chip v_fma_f32 ceiling).
// ---------------------------------------------------------------------------
__global__ __launch_bounds__(256) void gemm_fp32_kernel(const float* __restrict__ x,
                                                        const float* __restrict__ w1,
                                                        const float* __restrict__ b1,
                                                        float* __restrict__ h) {
    __shared__ float As[2][16][132] __attribute__((aligned(16)));   // [buf][k][m]
    __shared__ float Bs[2][16][132] __attribute__((aligned(16)));   // [buf][k][n]
    const int tid = threadIdx.x;
    const int n0 = blockIdx.x * 128;
    const int m0 = blockIdx.y * 128;
    const int tx = tid & 15;
    const int ty = tid >> 4;
    const int r  = tid >> 2;
    const int c  = (tid & 3) << 2;

    const int nb0 = n0 + r;
    const int nb1 = (n0 + r + 64 < N_HID) ? (n0 + r + 64) : (N_HID - 1);

    const float* xp0 = x  + (size_t)(m0 + r)      * IN_DIM + c;
    const float* xp1 = x  + (size_t)(m0 + r + 64) * IN_DIM + c;
    const float* wp0 = w1 + (size_t)nb0           * IN_DIM + c;
    const float* wp1 = w1 + (size_t)nb1           * IN_DIM + c;

    float4 pa0 = *(const float4*)(xp0);
    float4 pa1 = *(const float4*)(xp1);
    float4 pb0 = *(const float4*)(wp0);
    float4 pb1 = *(const float4*)(wp1);

    float acc[8][8] = {};
    int buf = 0;

    for (int k0 = 0; k0 < IN_DIM; k0 += 16) {
        float (*A)[132] = As[buf];
        float (*Bv)[132] = Bs[buf];
        A[c + 0][r] = pa0.x;  A[c + 1][r] = pa0.y;  A[c + 2][r] = pa0.z;  A[c + 3][r] = pa0.w;
        A[c + 0][r + 64] = pa1.x;  A[c + 1][r + 64] = pa1.y;  A[c + 2][r + 64] = pa1.z;  A[c + 3][r + 64] = pa1.w;
        Bv[c + 0][r] = pb0.x;  Bv[c + 1][r] = pb0.y;  Bv[c + 2][r] = pb0.z;  Bv[c + 3][r] = pb0.w;
        Bv[c + 0][r + 64] = pb1.x; Bv[c + 1][r + 64] = pb1.y; Bv[c + 2][r + 64] = pb1.z; Bv[c + 3][r + 64] = pb1.w;
        __syncthreads();

        const int kn = (k0 + 16 < IN_DIM) ? (k0 + 16) : 0;
        pa0 = *(const float4*)(xp0 + kn);
        pa1 = *(const float4*)(xp1 + kn);
        pb0 = *(const float4*)(wp0 + kn);
        pb1 = *(const float4*)(wp1 + kn);

        #pragma unroll
        for (int kk = 0; kk < 16; ++kk) {
            float a[8], b[8];
            *(float4*)&a[0] = *(const float4*)&A[kk][ty * 4];
            *(float4*)&a[4] = *(const float4*)&A[kk][64 + ty * 4];
            *(float4*)&b[0] = *(const float4*)&Bv[kk][tx * 4];
            *(float4*)&b[4] = *(const float4*)&Bv[kk][64 + tx * 4];
            #pragma unroll
            for (int i = 0; i < 8; ++i)
                #pragma unroll
                for (int j = 0; j < 8; ++j)
                    acc[i][j] = fmaf(a[i], b[j], acc[i][j]);
        }
        buf ^= 1;
    }

    const int nlo = n0 + tx * 4;
    const int nhi = n0 + 64 + tx * 4;
    #pragma unroll
    for (int i = 0; i < 8; ++i) {
        const int m = m0 + ((i < 4) ? (ty * 4 + i) : (64 + ty * 4 + (i - 4)));
        float* hrow = h + (size_t)m * N_HID;
        float4 v;
        v.x = acc[i][0] + b1[nlo + 0];
        v.y = acc[i][1] + b1[nlo + 1];
        v.z = acc[i][2] + b1[nlo + 2];
        v.w = acc[i][3] + b1[nlo + 3];
        *(float4*)(hrow + nlo) = v;
        if (nhi + 3 < N_HID) {
            float4 w;
            w.x = acc[i][4] + b1[nhi + 0];
            w.y = acc[i][5] + b1[nhi + 1];
            w.z = acc[i][6] + b1[nhi + 2];
            w.w = acc[i][7] + b1[nhi + 3];
            *(float4*)(hrow + nhi) = w;
        } else {
            #pragma unroll
            for (int j = 0; j < 4; ++j)
                if (nhi + j < N_HID) hrow[nhi + j] = acc[i][4 + j] + b1[nhi + j];
        }
    }
}

// ---------------------------------------------------------------------------
// Phase 2: one row per wave, 4 rows/block, zero __syncthreads.
// NEW vs round 8: (1) radix EARLY-EXIT — after 2 passes (16 bits) the chosen
// bin count is 1 in ~97% of rows; then the boundary key is found directly by
// a 32-slot compare+ballot instead of two more passes.  Else-branch runs the
// original passes 1,0 -> tkey/take_eq bit-identical in all cases.
// (2) winners compacted as INDEX only (h reloaded from global in the gather,
// L2/L3-warm) -> 32 fewer live VGPRs during the radix.  (3) parallel
// epilogue: lanes 0-9 each one expf/logf, coalesced store.
// ---------------------------------------------------------------------------
__global__ __launch_bounds__(256) void topk_logits_kernel(const float* __restrict__ h,
                                                          const float* __restrict__ boost,
                                                          const float* __restrict__ w2t,
                                                          const float* __restrict__ b2,
                                                          float* __restrict__ out) {
    __shared__ unsigned shist[4 * 256] __attribute__((aligned(16)));
    __shared__ unsigned swin[4][K_WIN] __attribute__((aligned(16)));
    const int wv   = threadIdx.x >> 6;
    const int lane = threadIdx.x & 63;
    const int row  = blockIdx.x * 4 + wv;
    unsigned* hist = &shist[wv * 256];

    const float* hrow = h + (size_t)row * N_HID;
    unsigned key[8][4];

    #pragma unroll
    for (int s = 0; s < 8; ++s) {
        const int idx4 = s * 64 + lane;
        if (idx4 < N_HID / 4) {
            float4 hv = *(const float4*)(hrow + idx4 * 4);
            float4 bv = *(const float4*)(boost + idx4 * 4);
            unsigned u0 = __float_as_uint(hv.x * bv.x);
            unsigned u1 = __float_as_uint(hv.y * bv.y);
            unsigned u2 = __float_as_uint(hv.z * bv.z);
            unsigned u3 = __float_as_uint(hv.w * bv.w);
            key[s][0] = (u0 >> 31) ? ~u0 : (u0 | 0x80000000u);
            key[s][1] = (u1 >> 31) ? ~u1 : (u1 | 0x80000000u);
            key[s][2] = (u2 >> 31) ? ~u2 : (u2 | 0x80000000u);
            key[s][3] = (u3 >> 31) ? ~u3 : (u3 | 0x80000000u);
        } else {
            key[s][0] = key[s][1] = key[s][2] = key[s][3] = 0u;
        }
    }

    unsigned pref = 0u;
    int r = K_WIN;
    int cnt = 0;

    // pack layout: bin[8b] << 22 | cnt[11b] << 11 | newr[11b]   (all < 2048)
    #pragma unroll
    for (int pass = 3; pass >= 2; --pass) {
        const int shift = pass * 8;
        const unsigned himask = (pass == 3) ? 0u : (0xFFFFFFFFu << (shift + 8));
        hist[lane] = 0u; hist[lane + 64] = 0u; hist[lane + 128] = 0u; hist[lane + 192] = 0u;
        __builtin_amdgcn_wave_barrier();
        #pragma unroll
        for (int s = 0; s < 8; ++s)
            #pragma unroll
            for (int j = 0; j < 4; ++j) {
                unsigned k = key[s][j];
                if (((k ^ pref) & himask) == 0u)
                    atomicAdd(&hist[(k >> shift) & 255u], 1u);
            }
        __builtin_amdgcn_wave_barrier();
        uint4 hv = *(const uint4*)&hist[lane * 4];
        unsigned tot = hv.x + hv.y + hv.z + hv.w;
        unsigned run = tot;
        #pragma unroll
        for (int off = 1; off < 64; off <<= 1) {
            unsigned t = (unsigned)__shfl_down((int)run, off);
            if (lane + off < 64) run += t;
        }
        const int above = (int)(run - tot);
        const int i3 = above + (int)hv.w;
        const int i2 = i3 + (int)hv.z;
        const int i1 = i2 + (int)hv.y;
        const int i0 = i1 + (int)hv.x;
        int fq = -1, fex = 0, fcnt = 0;
        if (i0 >= r && i1 < r)    { fq = 0; fex = i1;    fcnt = i0 - i1; }
        if (i1 >= r && i2 < r)    { fq = 1; fex = i2;    fcnt = i1 - i2; }
        if (i2 >= r && i3 < r)    { fq = 2; fex = i3;    fcnt = i2 - i3; }
        if (i3 >= r && above < r) { fq = 3; fex = above; fcnt = i3 - above; }
        unsigned long long fm = __ballot(fq >= 0);
        int src = __builtin_ctzll(fm);
        unsigned pack = (fq >= 0)
            ? (((unsigned)(lane * 4 + fq) << 22) | ((unsigned)fcnt << 11) |
               (unsigned)(r - fex)) : 0u;
        pack = (unsigned)__shfl((int)pack, src);
        pref |= (pack >> 22) << shift;
        r   = (int)(pack & 0x7FFu);
        cnt = (int)((pack >> 11) & 0x7FFu);
    }

    unsigned tkey;
    if (cnt == 1) {
        // unique key matches the 16-bit prefix: find it directly
        unsigned found = 0u;
        bool has = false;
        #pragma unroll
        for (int s = 0; s < 8; ++s)
            #pragma unroll
            for (int j = 0; j < 4; ++j) {
                unsigned k = key[s][j];
                if ((k & 0xFFFF0000u) == pref) { found = k; has = true; }
            }
        unsigned long long fm = __ballot(has);
        int src = __builtin_ctzll(fm);
        tkey = (unsigned)__shfl((int)found, src);
    } else {
        #pragma unroll
        for (int pass = 1; pass >= 0; --pass) {
            const int shift = pass * 8;
            const unsigned himask = 0xFFFFFFFFu << (shift + 8);
            hist[lane] = 0u; hist[lane + 64] = 0u; hist[lane + 128] = 0u; hist[lane + 192] = 0u;
            __builtin_amdgcn_wave_barrier();
            #pragma unroll
            for (int s = 0; s < 8; ++s)
                #pragma unroll
                for (int j = 0; j < 4; ++j) {
                    unsigned k = key[s][j];
                    if (((k ^ pref) & himask) == 0u)
                        atomicAdd(&hist[(k >> shift) & 255u], 1u);
                }
            __builtin_amdgcn_wave_barrier();
            uint4 hv = *(const uint4*)&hist[lane * 4];
            unsigned tot = hv.x + hv.y + hv.z + hv.w;
            unsigned run = tot;
            #pragma unroll
            for (int off = 1; off < 64; off <<= 1) {
                unsigned t = (unsigned)__shfl_down((int)run, off);
                if (lane + off < 64) run += t;
            }
            const int above = (int)(run - tot);
            const int i3 = above + (int)hv.w;
            const int i2 = i3 + (int)hv.z;
            const int i1 = i2 + (int)hv.y;
            const int i0 = i1 + (int)hv.x;
            int fq = -1, fex = 0;
            if (i0 >= r && i1 < r)    { fq = 0; fex = i1; }
            if (i1 >= r && i2 < r)    { fq = 1; fex = i2; }
            if (i2 >= r && i3 < r)    { fq = 2; fex = i3; }
            if (i3 >= r && above < r) { fq = 3; fex = above; }
            unsigned long long fm = __ballot(fq >= 0);
            int src = __builtin_ctzll(fm);
            unsigned pack = (fq >= 0)
                ? (((unsigned)(lane * 4 + fq) << 22) | (unsigned)(r - fex)) : 0u;
            pack = (unsigned)__shfl((int)pack, src);
            pref |= (pack >> 22) << shift;
            r = (int)(pack & 0x7FFu);
        }
        tkey = pref;
    }
    const int take_eq = r;

    // Winner identification (identical tie-break) + index compaction to LDS.
    int base = 0;
    int run_eq = 0;
    #pragma unroll
    for (int s = 0; s < 8; ++s) {
        const int idx4 = s * 64 + lane;
        bool gt[4], eq[4];
        #pragma unroll
        for (int j = 0; j < 4; ++j) {
            unsigned k = key[s][j];
            gt[j] = (k > tkey);
            eq[j] = (k == tkey);
        }
        unsigned long long em0 = __ballot(eq[0]);
        unsigned long long em1 = __ballot(eq[1]);
        unsigned long long em2 = __ballot(eq[2]);
        unsigned long long em3 = __ballot(eq[3]);
        const unsigned long long lt = (1ull << lane) - 1ull;
        const int base_lt = __popcll(em0 & lt) + __popcll(em1 & lt) +
                            __popcll(em2 & lt) + __popcll(em3 & lt);
        int own = 0;
        #pragma unroll
        for (int j = 0; j < 4; ++j) {
            bool win = gt[j];
            if (eq[j]) {
                win = (run_eq + base_lt + own < take_eq);
                ++own;
            }
            unsigned long long wm = __ballot(win);
            if (win) {
                const int pos = base + __popcll(wm & lt);
                swin[wv][pos] = (unsigned)(idx4 * 4 + j);
            }
            base += __popcll(wm);
        }
        run_eq += __popcll(em0) + __popcll(em1) + __popcll(em2) + __popcll(em3);
    }
    __builtin_amdgcn_wave_barrier();

    // Uniform gather: exactly K_WIN winners; h reloaded (L2/L3-warm).
    float l[10];
    #pragma unroll
    for (int cc = 0; cc < 10; ++cc) l[cc] = 0.f;
    #pragma unroll
    for (int t = 0; t < 4; ++t) {
        const bool act = (t < 3) || (lane < K_WIN - 192);
        if (act) {
            const unsigned widx = swin[wv][t * 64 + lane];
            const float hv = hrow[widx];
            const float* wr = w2t + (size_t)widx * 12;
            float4 wa = *(const float4*)wr;
            float4 wb = *(const float4*)(wr + 4);
            float2 wc = *(const float2*)(wr + 8);
            l[0] = fmaf(hv, wa.x, l[0]);
            l[1] = fmaf(hv, wa.y, l[1]);
            l[2] = fmaf(hv, wa.z, l[2]);
            l[3] = fmaf(hv, wa.w, l[3]);
            l[4] = fmaf(hv, wb.x, l[4]);
            l[5] = fmaf(hv, wb.y, l[5]);
            l[6] = fmaf(hv, wb.z, l[6]);
            l[7] = fmaf(hv, wb.w, l[7]);
            l[8] = fmaf(hv, wc.x, l[8]);
            l[9] = fmaf(hv, wc.y, l[9]);
        }
    }
    #pragma unroll
    for (int off = 32; off > 0; off >>= 1)
        #pragma unroll
        for (int cc = 0; cc < 10; ++cc)
            l[cc] += __shfl_down(l[cc], off);

    // Parallel epilogue: lane 0 publishes logits; lanes 0-9 do exp/log.
    if (lane == 0) {
        #pragma unroll
        for (int cc = 0; cc < 10; ++cc)
            hist[cc] = __float_as_uint(l[cc] + b2[cc]);
    }
    __builtin_amdgcn_wave_barrier();
    if (lane < 16) {
        float lg = (lane < 10) ? __uint_as_float(hist[lane]) : -__builtin_inff();
        float mx = lg;
        #pragma unroll
        for (int off = 8; off >= 1; off >>= 1)
            mx = fmaxf(mx, __shfl_xor(mx, off));
        float e = (lane < 10) ? expf(lg - mx) : 0.f;
        float sm = e;
        #pragma unroll
        for (int off = 8; off >= 1; off >>= 1)
            sm += __shfl_xor(sm, off);
        if (lane < 10)
            out[(size_t)row * 10 + lane] = lg - (mx + logf(sm));
    }
}

// ---------------------------------------------------------------------------
extern "C" void kernel_launch(void* const* d_in, const int* in_sizes, int n_in,
                              void* d_out, int out_size, void* d_ws, size_t ws_size,
                              hipStream_t stream) {
    const float* x    = (const float*)d_in[0];
    const float* w1   = (const float*)d_in[1];
    const float* b1   = (const float*)d_in[2];
    const float* w2   = (const float*)d_in[3];
    const float* b2   = (const float*)d_in[4];
    const float* duty = (const float*)d_in[5];
    float* out = (float*)d_out;

    const size_t hbytes = (size_t)B_ROWS * N_HID * sizeof(float);  // 131.072 MB
    float* h     = (float*)d_ws;
    float* boost = (float*)((char*)d_ws + hbytes);                 // 8 KB
    float* w2t   = (float*)((char*)d_ws + hbytes + 8192);          // 96 KB

    prep_kernel<<<(N_HID * 10 + 255) / 256, 256, 0, stream>>>(duty, w2, boost, w2t);
    gemm_fp32_kernel<<<dim3(16, 128), 256, 0, stream>>>(x, w1, b1, h);
    topk_logits_kernel<<<B_ROWS / 4, 256, 0, stream>>>(h, boost, w2t, b2, out);
}

// Round 10
// 573.264 us; speedup vs baseline: 1.2767x; 1.2767x over previous
//
#include <hip/hip_runtime.h>
#include <cmath>

#define B_ROWS 16384
#define IN_DIM 784
#define N_HID  2000
#define K_WIN  200
#define KPAD   800
#define EPS_MARGIN 1.5e-3f

typedef __attribute__((ext_vector_type(8))) short bf16x8;   // 8 bf16 = 4 VGPR
typedef __attribute__((ext_vector_type(4))) float floatx4;  // MFMA C/D

__device__ inline unsigned short bf16_rn_bits(float f) {
    unsigned u = __float_as_uint(f);
    return (unsigned short)((u + 0x7FFFu + ((u >> 16) & 1u)) >> 16);
}
__device__ inline unsigned mapkey(float f) {
    unsigned u = __float_as_uint(f);
    return (u >> 31) ? ~u : (u | 0x80000000u);
}
__device__ inline float unmapkey(unsigned k) {
    unsigned u = (k & 0x80000000u) ? (k & 0x7FFFFFFFu) : ~k;
    return __uint_as_float(u);
}

// ---------------------------------------------------------------------------
// Phase 0: boost[i] = expf(0.1f - duty[i]);  w2t[i*12+c] = w2[c*2000+i]
// ---------------------------------------------------------------------------
__global__ __launch_bounds__(256) void prep_kernel(const float* __restrict__ duty,
                                                   const float* __restrict__ w2,
                                                   float* __restrict__ boost,
                                                   float* __restrict__ w2t) {
    int t = blockIdx.x * 256 + threadIdx.x;
    if (t < N_HID) boost[t] = expf(0.1f - duty[t]);
    if (t < N_HID * 10) {
        int i = t / 10, c = t - i * 10;
        w2t[i * 12 + c] = w2[c * N_HID + i];
    }
}

// ---------------------------------------------------------------------------
// Phase 1: h' = x @ W1^T + b1 via SPLIT-BF16 MFMA (3 products: hh + hl + lh).
// |h' - h_fp32| <= ~3e-4 worst-case; the topk kernel's margin machinery
// recovers the EXACT canonical-fp32 winner set (see phase 2).
// Block 256 = 4 waves; block tile 128x128; wave tile 64x64 = 4x4 MFMA
// 16x16x32 tiles; K padded 784->800 (zeros).  In-register fp32->bf16 hi/lo
// split during staging; LDS row stride 40 ushorts (80 B: 16B-aligned b128
// reads, uniform 2-way banks = free per m136).
// ---------------------------------------------------------------------------
__global__ __launch_bounds__(256) void gemm_mfma_kernel(
        const float* __restrict__ x, const float* __restrict__ w1,
        const float* __restrict__ b1, float* __restrict__ h) {
    __shared__ unsigned short Ah[128][40] __attribute__((aligned(16)));
    __shared__ unsigned short Al[128][40] __attribute__((aligned(16)));
    __shared__ unsigned short Bh[128][40] __attribute__((aligned(16)));
    __shared__ unsigned short Bl[128][40] __attribute__((aligned(16)));
    const int tid  = threadIdx.x;
    const int wv   = tid >> 6, lane = tid & 63;
    const int quad = lane >> 4, l15 = lane & 15;
    const int m0 = blockIdx.y * 128, n0 = blockIdx.x * 128;
    const int wm = (wv >> 1) * 64, wn = (wv & 1) * 64;

    // staging: thread t -> row t>>1 (0..127), k-offset (t&1)*16
    const int srow = tid >> 1;
    const int skq  = (tid & 1) * 16;
    const float* xs = x + (size_t)(m0 + srow) * IN_DIM;
    int bn = n0 + srow; if (bn > N_HID - 1) bn = N_HID - 1;
    const float* ws = w1 + (size_t)bn * IN_DIM;

    floatx4 acc[4][4];
    #pragma unroll
    for (int a = 0; a < 4; ++a)
        #pragma unroll
        for (int b = 0; b < 4; ++b)
            acc[a][b] = (floatx4){0.f, 0.f, 0.f, 0.f};

    for (int k0 = 0; k0 < KPAD; k0 += 32) {
        float vx[16], vw[16];
        const int kb = k0 + skq;
        if (kb < IN_DIM) {   // kb multiple of 16; kb<784 => kb+15<=783 valid
            #pragma unroll
            for (int q = 0; q < 4; ++q) {
                float4 a = *(const float4*)(xs + kb + q * 4);
                float4 b = *(const float4*)(ws + kb + q * 4);
                vx[q*4+0]=a.x; vx[q*4+1]=a.y; vx[q*4+2]=a.z; vx[q*4+3]=a.w;
                vw[q*4+0]=b.x; vw[q*4+1]=b.y; vw[q*4+2]=b.z; vw[q*4+3]=b.w;
            }
        } else {
            #pragma unroll
            for (int q = 0; q < 16; ++q) { vx[q] = 0.f; vw[q] = 0.f; }
        }
        __syncthreads();   // previous chunk's LDS reads complete

        bf16x8 xh0, xh1, xl0, xl1, wh0, wh1, wl0, wl1;
        #pragma unroll
        for (int q = 0; q < 16; ++q) {
            unsigned short hs = bf16_rn_bits(vx[q]);
            float hf = __uint_as_float(((unsigned)hs) << 16);
            unsigned short ls = bf16_rn_bits(vx[q] - hf);
            if (q < 8) { xh0[q] = (short)hs; xl0[q] = (short)ls; }
            else       { xh1[q-8] = (short)hs; xl1[q-8] = (short)ls; }
            unsigned short hw = bf16_rn_bits(vw[q]);
            float hwf = __uint_as_float(((unsigned)hw) << 16);
            unsigned short lw = bf16_rn_bits(vw[q] - hwf);
            if (q < 8) { wh0[q] = (short)hw; wl0[q] = (short)lw; }
            else       { wh1[q-8] = (short)hw; wl1[q-8] = (short)lw; }
        }
        *(bf16x8*)&Ah[srow][skq]     = xh0;
        *(bf16x8*)&Ah[srow][skq + 8] = xh1;
        *(bf16x8*)&Al[srow][skq]     = xl0;
        *(bf16x8*)&Al[srow][skq + 8] = xl1;
        *(bf16x8*)&Bh[srow][skq]     = wh0;
        *(bf16x8*)&Bh[srow][skq + 8] = wh1;
        *(bf16x8*)&Bl[srow][skq]     = wl0;
        *(bf16x8*)&Bl[srow][skq + 8] = wl1;
        __syncthreads();

        bf16x8 bhf[4], blf[4];
        #pragma unroll
        for (int ng = 0; ng < 4; ++ng) {
            const int br = wn + ng * 16 + l15;
            bhf[ng] = *(const bf16x8*)&Bh[br][quad * 8];
            blf[ng] = *(const bf16x8*)&Bl[br][quad * 8];
        }
        #pragma unroll
        for (int mg = 0; mg < 4; ++mg) {
            const int ar = wm + mg * 16 + l15;
            bf16x8 ah = *(const bf16x8*)&Ah[ar][quad * 8];
            bf16x8 al = *(const bf16x8*)&Al[ar][quad * 8];
            #pragma unroll
            for (int ng = 0; ng < 4; ++ng) {
                acc[mg][ng] = __builtin_amdgcn_mfma_f32_16x16x32_bf16(ah, bhf[ng], acc[mg][ng], 0, 0, 0);
                acc[mg][ng] = __builtin_amdgcn_mfma_f32_16x16x32_bf16(ah, blf[ng], acc[mg][ng], 0, 0, 0);
                acc[mg][ng] = __builtin_amdgcn_mfma_f32_16x16x32_bf16(al, bhf[ng], acc[mg][ng], 0, 0, 0);
            }
        }
    }

    // Epilogue: C/D layout col=lane&15 (n), row=quad*4+reg (m)  [m89/m91]
    #pragma unroll
    for (int ng = 0; ng < 4; ++ng) {
        const int n = n0 + wn + ng * 16 + l15;
        if (n < N_HID) {
            const float bv = b1[n];
            #pragma unroll
            for (int mg = 0; mg < 4; ++mg) {
                #pragma unroll
                for (int t = 0; t < 4; ++t) {
                    const int m = m0 + wm + mg * 16 + quad * 4 + t;
                    h[(size_t)m * N_HID + n] = acc[mg][ng][t] + bv;
                }
            }
        }
    }
}

// ---------------------------------------------------------------------------
// Phase 2: one row per wave, 4 rows/block, zero __syncthreads.
// Round-8 radix select (4-pass, per-wave hist) gives tkey = 200th APPROX key.
// Margin classification: sure (key > map(t'+EPS)) / contested (within +-EPS).
// Contested elements are recomputed EXACTLY in the canonical fp32 k-ascending
// order (one lane each, serial fmaf chain) and ranked exactly (index ties ->
// lower first) -> winner set == exact-fp32 top-k (order-stat l-inf coupling;
// EPS >= 5x the split-GEMM error bound).  Then round-8 compact gather.
// ---------------------------------------------------------------------------
__global__ __launch_bounds__(256) void topk_logits_kernel(
        const float* __restrict__ h, const float* __restrict__ x,
        const float* __restrict__ w1, const float* __restrict__ b1,
        const float* __restrict__ boost, const float* __restrict__ w2t,
        const float* __restrict__ b2, float* __restrict__ out) {
    __shared__ unsigned shist[4 * 256] __attribute__((aligned(16)));
    __shared__ uint2 swin[4][K_WIN] __attribute__((aligned(16)));
    __shared__ unsigned scon_idx[4][64];
    __shared__ unsigned scon_h[4][64];
    __shared__ unsigned scon_k[4][64];
    const int wv   = threadIdx.x >> 6;
    const int lane = threadIdx.x & 63;
    const int row  = blockIdx.x * 4 + wv;
    unsigned* hist = &shist[wv * 256];

    // prefill swin (safety against impossible margin-violation paths)
    swin[wv][lane] = make_uint2(0u, 0u);
    swin[wv][lane + 64] = make_uint2(0u, 0u);
    swin[wv][lane + 128] = make_uint2(0u, 0u);
    if (lane < 8) swin[wv][lane + 192] = make_uint2(0u, 0u);

    const float* hrow = h + (size_t)row * N_HID;
    float4 hreg[8];
    unsigned key[8][4];

    #pragma unroll
    for (int s = 0; s < 8; ++s) {
        const int idx4 = s * 64 + lane;
        if (idx4 < N_HID / 4) {
            float4 hv = *(const float4*)(hrow + idx4 * 4);
            float4 bv = *(const float4*)(boost + idx4 * 4);
            hreg[s] = hv;
            key[s][0] = mapkey(hv.x * bv.x);
            key[s][1] = mapkey(hv.y * bv.y);
            key[s][2] = mapkey(hv.z * bv.z);
            key[s][3] = mapkey(hv.w * bv.w);
        } else {
            hreg[s] = make_float4(0.f, 0.f, 0.f, 0.f);
            key[s][0] = key[s][1] = key[s][2] = key[s][3] = 0u;
        }
    }

    unsigned pref = 0u;
    int r = K_WIN;

    #pragma unroll
    for (int pass = 3; pass >= 0; --pass) {
        const int shift = pass * 8;
        const unsigned himask = (pass == 3) ? 0u : (0xFFFFFFFFu << (shift + 8));
        hist[lane] = 0u; hist[lane + 64] = 0u; hist[lane + 128] = 0u; hist[lane + 192] = 0u;
        __builtin_amdgcn_wave_barrier();
        #pragma unroll
        for (int s = 0; s < 8; ++s)
            #pragma unroll
            for (int j = 0; j < 4; ++j) {
                unsigned k = key[s][j];
                if (((k ^ pref) & himask) == 0u)
                    atomicAdd(&hist[(k >> shift) & 255u], 1u);
            }
        __builtin_amdgcn_wave_barrier();
        uint4 hv = *(const uint4*)&hist[lane * 4];
        unsigned tot = hv.x + hv.y + hv.z + hv.w;
        unsigned run = tot;
        #pragma unroll
        for (int off = 1; off < 64; off <<= 1) {
            unsigned t = (unsigned)__shfl_down((int)run, off);
            if (lane + off < 64) run += t;
        }
        const int above = (int)(run - tot);
        const int i3 = above + (int)hv.w;
        const int i2 = i3 + (int)hv.z;
        const int i1 = i2 + (int)hv.y;
        const int i0 = i1 + (int)hv.x;
        int fq = -1, fex = 0;
        if (i0 >= r && i1 < r)    { fq = 0; fex = i1; }
        if (i1 >= r && i2 < r)    { fq = 1; fex = i2; }
        if (i2 >= r && i3 < r)    { fq = 2; fex = i3; }
        if (i3 >= r && above < r) { fq = 3; fex = above; }
        unsigned long long fm = __ballot(fq >= 0);
        int src = __builtin_ctzll(fm);
        unsigned pack = (fq >= 0)
            ? (((unsigned)(lane * 4 + fq) << 16) | (unsigned)(r - fex)) : 0u;
        pack = (unsigned)__shfl((int)pack, src);
        pref |= (pack >> 16) << shift;
        r = (int)(pack & 0xFFFFu);
    }

    // margin thresholds in key space
    const float tval = unmapkey(pref);
    const unsigned kin  = mapkey(tval + EPS_MARGIN);   // sure:      key >  kin
    const unsigned kout = mapkey(tval - EPS_MARGIN);   // contested: key >= kout

    int nsure = 0, ncon = 0;
    #pragma unroll
    for (int s = 0; s < 8; ++s) {
        const int idx4 = s * 64 + lane;
        const float* hp = (const float*)&hreg[s];
        #pragma unroll
        for (int j = 0; j < 4; ++j) {
            unsigned k = key[s][j];
            bool sure = (k > kin);
            bool cont = (!sure) && (k >= kout);
            unsigned long long sm = __ballot(sure);
            unsigned long long cm = __ballot(cont);
            const unsigned long long lt = (1ull << lane) - 1ull;
            if (sure) {
                int pos = nsure + __popcll(sm & lt);
                if (pos < K_WIN)
                    swin[wv][pos] = make_uint2((unsigned)(idx4 * 4 + j),
                                               __float_as_uint(hp[j]));
            }
            if (cont) {
                int pos = ncon + __popcll(cm & lt);
                if (pos < 64) {
                    scon_idx[wv][pos] = (unsigned)(idx4 * 4 + j);
                    scon_h[wv][pos]   = __float_as_uint(hp[j]);
                }
            }
            nsure += __popcll(sm);
            ncon  += __popcll(cm);
        }
    }
    if (ncon > 64) ncon = 64;
    __builtin_amdgcn_wave_barrier();

    // exact canonical-fp32 recompute for contested elements (k ascending)
    unsigned myidx = 0, kex = 0;
    const bool act = (lane < ncon);
    if (act) {
        myidx = scon_idx[wv][lane];
        const float* xr = x + (size_t)row * IN_DIM;
        const float* wr = w1 + (size_t)myidx * IN_DIM;
        float a = 0.f;
        for (int k = 0; k < IN_DIM; ++k)
            a = fmaf(xr[k], wr[k], a);
        const float bex = (a + b1[myidx]) * boost[myidx];
        kex = mapkey(bex);
        scon_k[wv][lane] = kex;
    }
    __builtin_amdgcn_wave_barrier();

    const int nsel = K_WIN - nsure;
    if (act) {
        int rnk = 0;
        for (int q = 0; q < ncon; ++q) {
            unsigned kq = scon_k[wv][q];
            unsigned iq = scon_idx[wv][q];
            rnk += (int)((kq > kex) || (kq == kex && iq < myidx));
        }
        if (rnk < nsel) {
            int pos = nsure + rnk;     // < K_WIN by construction
            if (pos >= 0 && pos < K_WIN)
                swin[wv][pos] = make_uint2(myidx, scon_h[wv][lane]);
        }
    }
    __builtin_amdgcn_wave_barrier();

    // uniform gather over exactly K_WIN winners (round-8 structure)
    float l[10];
    #pragma unroll
    for (int cc = 0; cc < 10; ++cc) l[cc] = 0.f;
    #pragma unroll
    for (int t = 0; t < 4; ++t) {
        const bool a2 = (t < 3) || (lane < K_WIN - 192);
        if (a2) {
            const uint2 wrec = swin[wv][t * 64 + lane];
            const float hv = __uint_as_float(wrec.y);
            const float* wr = w2t + (size_t)wrec.x * 12;
            float4 wa = *(const float4*)wr;
            float4 wb = *(const float4*)(wr + 4);
            float2 wc = *(const float2*)(wr + 8);
            l[0] = fmaf(hv, wa.x, l[0]);
            l[1] = fmaf(hv, wa.y, l[1]);
            l[2] = fmaf(hv, wa.z, l[2]);
            l[3] = fmaf(hv, wa.w, l[3]);
            l[4] = fmaf(hv, wb.x, l[4]);
            l[5] = fmaf(hv, wb.y, l[5]);
            l[6] = fmaf(hv, wb.z, l[6]);
            l[7] = fmaf(hv, wb.w, l[7]);
            l[8] = fmaf(hv, wc.x, l[8]);
            l[9] = fmaf(hv, wc.y, l[9]);
        }
    }
    #pragma unroll
    for (int off = 32; off > 0; off >>= 1)
        #pragma unroll
        for (int cc = 0; cc < 10; ++cc)
            l[cc] += __shfl_down(l[cc], off);

    if (lane == 0) {
        float lg[10];
        #pragma unroll
        for (int cc = 0; cc < 10; ++cc) lg[cc] = l[cc] + b2[cc];
        float mx = lg[0];
        #pragma unroll
        for (int cc = 1; cc < 10; ++cc) mx = fmaxf(mx, lg[cc]);
        float s = 0.f;
        #pragma unroll
        for (int cc = 0; cc < 10; ++cc) s += expf(lg[cc] - mx);
        const float lse = mx + logf(s);
        float* orow = out + (size_t)row * 10;
        #pragma unroll
        for (int cc = 0; cc < 10; ++cc) orow[cc] = lg[cc] - lse;
    }
}

// ---------------------------------------------------------------------------
extern "C" void kernel_launch(void* const* d_in, const int* in_sizes, int n_in,
                              void* d_out, int out_size, void* d_ws, size_t ws_size,
                              hipStream_t stream) {
    const float* x    = (const float*)d_in[0];
    const float* w1   = (const float*)d_in[1];
    const float* b1   = (const float*)d_in[2];
    const float* w2   = (const float*)d_in[3];
    const float* b2   = (const float*)d_in[4];
    const float* duty = (const float*)d_in[5];
    float* out = (float*)d_out;

    const size_t hbytes = (size_t)B_ROWS * N_HID * sizeof(float);  // 131.072 MB
    float* h     = (float*)d_ws;
    float* boost = (float*)((char*)d_ws + hbytes);                 // 8 KB
    float* w2t   = (float*)((char*)d_ws + hbytes + 8192);          // 96 KB

    prep_kernel<<<(N_HID * 10 + 255) / 256, 256, 0, stream>>>(duty, w2, boost, w2t);
    gemm_mfma_kernel<<<dim3(16, 128), 256, 0, stream>>>(x, w1, b1, h);
    topk_logits_kernel<<<B_ROWS / 4, 256, 0, stream>>>(h, x, w1, b1, boost, w2t, b2, out);
}